// Round 14
// baseline (609.641 us; speedup 1.0000x reference)
//
#include <hip/hip_runtime.h>

#define N_NODES 100000
#define N_EDGES 1600000
#define CDIM    128
#define BATCH   50000
#define NLAYERS 3
#define EPS_BN  1e-5f
#define LPAD    136   // LDS row stride in bf16 elems (272 B)

#define NBUCK   512
#define BW      196     // 512*196 = 100352 >= N_NODES
#define EPB     4096    // edges per block in bucket_fill
#define NEB     ((N_EDGES + EPB - 1) / EPB)   // 391
#define EBCAP   3584    // fixed ebuf slots/bucket (mean 3125, sd 56 -> +8 sigma)

typedef __attribute__((ext_vector_type(8))) short short8;   // 8 bf16
typedef __attribute__((ext_vector_type(4))) float floatx4;  // MFMA acc

__device__ __forceinline__ unsigned short f2bf(float f) {
    unsigned int u = __float_as_uint(f);
    u = u + 0x7FFFu + ((u >> 16) & 1u);   // RTNE
    return (unsigned short)(u >> 16);
}
__device__ __forceinline__ void unpk(unsigned int u, float& lo, float& hi) {
    lo = __uint_as_float(u << 16);
    hi = __uint_as_float(u & 0xFFFF0000u);
}
__device__ __forceinline__ unsigned int pk2(float lo, float hi) {
    return (unsigned int)f2bf(lo) | ((unsigned int)f2bf(hi) << 16);
}

// Workspace float-offsets.
// CRITICAL (R11 lesson): hb0/hb1 bases MUST be 256-B aligned (2 lines/row).
#define OFF_HB0   6400000
#define OFF_HB1   12800000
#define OFF_SC    19200000
#define OFF_RP    19201152   // rowptr, N+1 ints
#define OFF_BCNT  19301184   // 512 (count, fixed-region cursor)
#define OFF_ELIST 19302752   // E ints (exact, contiguous)
#define OFF_EBUF  20902752   // 512*3584 packed uints
#define OFF_WCAT  22737760   // 3*128*256 bf16
#define OFF_WH1   22786912   // 128*128 bf16
#define OFF_WH2   22795104   // 64*128 bf16

// ---------------------------------------------------------------------------
// Mega setup kernel: convert_x / convert_w / convert_whead / fold_bn + bcnt=0
// ---------------------------------------------------------------------------
#define XBLK 12500
#define WBLK 384
#define HBLK 96
__global__ __launch_bounds__(256) void setup_all(
        const float* __restrict__ x,
        const float* __restrict__ Wl, const float* __restrict__ Wr,
        const float* __restrict__ cW1, const float* __restrict__ cW2,
        const float* __restrict__ g, const float* __restrict__ b,
        const float* __restrict__ m, const float* __restrict__ v,
        const float* __restrict__ cg1, const float* __restrict__ cbe1,
        const float* __restrict__ cm1, const float* __restrict__ cv1,
        const float* __restrict__ cg2, const float* __restrict__ cbe2,
        const float* __restrict__ cm2, const float* __restrict__ cv2,
        float* __restrict__ ws) {
    int blk = blockIdx.x;
    int tid = threadIdx.x;
    unsigned short* xb = (unsigned short*)ws;

    if (blk < XBLK) {
        int i = blk * 256 + tid;
        float4 vv = ((const float4*)x)[i];
        ushort4 o;
        o.x = f2bf(vv.x); o.y = f2bf(vv.y); o.z = f2bf(vv.z); o.w = f2bf(vv.w);
        ((ushort4*)xb)[i] = o;
        return;
    }
    if (blk < XBLK + WBLK) {
        unsigned short* wcat = (unsigned short*)(ws + OFF_WCAT);
        int i = (blk - XBLK) * 256 + tid;
        int l = i >> 15;
        int n = (i >> 8) & 127;
        int k = i & 255;
        float w = (k < CDIM) ? Wl[((size_t)l * CDIM + k) * CDIM + n]
                             : Wr[((size_t)l * CDIM + (k - CDIM)) * CDIM + n];
        wcat[i] = f2bf(w);
        return;
    }
    if (blk < XBLK + WBLK + HBLK) {
        unsigned short* wh1 = (unsigned short*)(ws + OFF_WH1);
        unsigned short* wh2 = (unsigned short*)(ws + OFF_WH2);
        int i = (blk - XBLK - WBLK) * 256 + tid;
        if (i < 128 * 128) {
            int n = i >> 7, k = i & 127;
            wh1[i] = f2bf(cW1[k * 128 + n]);
        } else if (i < 128 * 128 + 64 * 128) {
            int j = i - 128 * 128;
            int n = j >> 7, k = j & 127;
            wh2[j] = f2bf(cW2[k * 64 + n]);
        }
        return;
    }
    // misc block: fold BN, zero bcnt
    float* sc = ws + OFF_SC;
    int* bcnt = (int*)(ws + OFF_BCNT);
    for (int i = tid; i < NLAYERS * CDIM; i += 256) {
        float s = g[i] * rsqrtf(v[i] + EPS_BN);
        sc[i] = s;
        sc[NLAYERS * CDIM + i] = b[i] - m[i] * s;
    }
    if (tid < CDIM) {
        float s = cg1[tid] * rsqrtf(cv1[tid] + EPS_BN);
        sc[768 + tid] = s;
        sc[896 + tid] = cbe1[tid] - cm1[tid] * s;
    }
    if (tid < 64) {
        float s = cg2[tid] * rsqrtf(cv2[tid] + EPS_BN);
        sc[1024 + tid] = s;
        sc[1088 + tid] = cbe2[tid] - cm2[tid] * s;
    }
    for (int i = tid; i < NBUCK; i += 256) bcnt[i] = 0;
}

// ---------------------------------------------------------------------------
// bucket_fill: fixed per-bucket ebuf regions (b*EBCAP); bcnt = cursor+count.
// int4 ei reads + LDS-cached bucket ids.
// ---------------------------------------------------------------------------
__global__ __launch_bounds__(256) void bucket_fill(const int* __restrict__ ei,
                                                   int* __restrict__ bcnt,
                                                   unsigned int* __restrict__ ebuf) {
    __shared__ unsigned int st[EPB];      // 16 KB
    __shared__ unsigned short sb[EPB];    // 8 KB
    __shared__ int lh[NBUCK];
    __shared__ int gb[NBUCK];
    __shared__ int lc[NBUCK];
    int tid = threadIdx.x;
    for (int t = tid; t < NBUCK; t += 256) { lh[t] = 0; lc[t] = 0; }
    __syncthreads();
    int base = blockIdx.x * EPB;
    int cnt = min(EPB, N_EDGES - base);    // always multiple of 4
    for (int k = tid; k < cnt / 4; k += 256) {
        int4 s4 = ((const int4*)(ei + base))[k];
        int4 d4 = ((const int4*)(ei + N_EDGES + base))[k];
        int i0 = k * 4;
#pragma unroll
        for (int q = 0; q < 4; ++q) {
            int s = (q == 0) ? s4.x : (q == 1) ? s4.y : (q == 2) ? s4.z : s4.w;
            int d = (q == 0) ? d4.x : (q == 1) ? d4.y : (q == 2) ? d4.z : d4.w;
            int bk = (unsigned)d / BW;
            int ld = d - bk * BW;
            st[i0 + q] = (unsigned)s | ((unsigned)ld << 17);
            sb[i0 + q] = (unsigned short)bk;
            atomicAdd(&lh[bk], 1);
        }
    }
    __syncthreads();
    for (int t = tid; t < NBUCK; t += 256) {
        int c = lh[t];
        gb[t] = c ? (t * EBCAP + atomicAdd(&bcnt[t], c)) : 0;
    }
    __syncthreads();
    for (int i = tid; i < cnt; i += 256) {
        int bk = sb[i];
        int pos = gb[bk] + atomicAdd(&lc[bk], 1);
        ebuf[pos] = st[i];
    }
}

// ---------------------------------------------------------------------------
// bucket_csr: one block per bucket. Internal 512-wide scan of bcnt gives the
// exact elist base (no separate scan dispatch). Local per-dst CSR in LDS,
// coalesced elist/rowptr out.
// ---------------------------------------------------------------------------
__global__ __launch_bounds__(256) void bucket_csr(const unsigned int* __restrict__ ebuf,
                                                  const int* __restrict__ bcnt,
                                                  int* __restrict__ elist,
                                                  int* __restrict__ rowptr) {
    __shared__ int sbb[NBUCK];            // 2 KB: bucket-count prefix
    __shared__ unsigned int st[EBCAP];    // 14 KB
    __shared__ int out[EBCAP];            // 14 KB
    __shared__ int h[256], sscan[256], pre[256], cur[256];
    int b = blockIdx.x;
    int tid = threadIdx.x;
    int cnt = min(bcnt[b], EBCAP);

    // inclusive scan of all 512 bucket counts (256 threads x 2 elems)
    sbb[tid] = bcnt[tid];
    sbb[tid + 256] = bcnt[tid + 256];
    h[tid] = 0; cur[tid] = 0;
    __syncthreads();
    for (int off = 1; off < NBUCK; off <<= 1) {
        int v0 = (tid >= off) ? sbb[tid - off] : 0;
        int t2 = tid + 256;
        int v1 = sbb[t2 - off];   // t2 >= 256 > off always
        __syncthreads();
        sbb[tid] += v0;
        sbb[t2] += v1;
        __syncthreads();
    }
    int obase = (b == 0) ? 0 : sbb[b - 1];

    int ebase = b * EBCAP;
    for (int i = tid; i < cnt; i += 256) {
        unsigned int u = ebuf[ebase + i];
        st[i] = u;
        atomicAdd(&h[u >> 17], 1);
    }
    __syncthreads();
    sscan[tid] = h[tid];
    __syncthreads();
    for (int off = 1; off < 256; off <<= 1) {
        int v = (tid >= off) ? sscan[tid - off] : 0;
        __syncthreads();
        sscan[tid] += v;
        __syncthreads();
    }
    pre[tid] = sscan[tid] - h[tid];
    __syncthreads();
    for (int i = tid; i < cnt; i += 256) {
        unsigned int u = st[i];
        int ld = u >> 17;
        int pos = pre[ld] + atomicAdd(&cur[ld], 1);
        out[pos] = (int)(u & 0x1FFFFu);
    }
    __syncthreads();
    for (int i = tid; i < cnt; i += 256) elist[obase + i] = out[i];
    int gn = b * BW + tid;
    if (tid < BW && gn < N_NODES) rowptr[gn] = obase + pre[tid];
    if (b == 0 && tid == 0) rowptr[N_NODES] = N_EDGES;
}

// ---------------------------------------------------------------------------
// Fused SAGE layer: 8-deep gather (8 rows in flight per 16-lane sub-half,
// 2x R13 depth), 4-chunk + scalar tail, MFMA GEMM, coalesced bf16 C store.
// ---------------------------------------------------------------------------
__global__ __launch_bounds__(256, 8) void sage_fused(const int* __restrict__ rowptr,
                                                     const int* __restrict__ elist,
                                                     const unsigned short* __restrict__ hin,
                                                     unsigned short* __restrict__ hout,
                                                     const unsigned short* __restrict__ wcat,
                                                     const float* __restrict__ bl,
                                                     const float* __restrict__ scale,
                                                     const float* __restrict__ shift) {
    __shared__ unsigned short sA[32][LPAD];
    __shared__ unsigned short sH[32][LPAD];

    int row0 = blockIdx.x * 32;
    int tid = threadIdx.x;
    int lane = tid & 31;
    int grp = tid >> 5;       // 8 node-groups
    int sub = lane >> 4;      // 0/1: chunk parity
    int li  = lane & 15;      // 16 lanes x 8 channels

    for (int rr = 0; rr < 4; ++rr) {
        int r = rr * 8 + grp;
        int node = row0 + r;
        int beg = rowptr[node];
        int end = rowptr[node + 1];
        float a0 = 0.f, a1 = 0.f, a2 = 0.f, a3 = 0.f,
              a4 = 0.f, a5 = 0.f, a6 = 0.f, a7 = 0.f;
        int j = beg + sub * 8;
        for (; j + 8 <= end; j += 16) {
            int s0 = elist[j],     s1 = elist[j + 1], s2 = elist[j + 2], s3 = elist[j + 3];
            int s4 = elist[j + 4], s5 = elist[j + 5], s6 = elist[j + 6], s7 = elist[j + 7];
            uint4 u0 = *((const uint4*)(hin + (size_t)s0 * CDIM + li * 8));
            uint4 u1 = *((const uint4*)(hin + (size_t)s1 * CDIM + li * 8));
            uint4 u2 = *((const uint4*)(hin + (size_t)s2 * CDIM + li * 8));
            uint4 u3 = *((const uint4*)(hin + (size_t)s3 * CDIM + li * 8));
            uint4 u4 = *((const uint4*)(hin + (size_t)s4 * CDIM + li * 8));
            uint4 u5 = *((const uint4*)(hin + (size_t)s5 * CDIM + li * 8));
            uint4 u6 = *((const uint4*)(hin + (size_t)s6 * CDIM + li * 8));
            uint4 u7 = *((const uint4*)(hin + (size_t)s7 * CDIM + li * 8));
            float lo, hi;
            unpk(u0.x, lo, hi); a0 += lo; a1 += hi;
            unpk(u0.y, lo, hi); a2 += lo; a3 += hi;
            unpk(u0.z, lo, hi); a4 += lo; a5 += hi;
            unpk(u0.w, lo, hi); a6 += lo; a7 += hi;
            unpk(u1.x, lo, hi); a0 += lo; a1 += hi;
            unpk(u1.y, lo, hi); a2 += lo; a3 += hi;
            unpk(u1.z, lo, hi); a4 += lo; a5 += hi;
            unpk(u1.w, lo, hi); a6 += lo; a7 += hi;
            unpk(u2.x, lo, hi); a0 += lo; a1 += hi;
            unpk(u2.y, lo, hi); a2 += lo; a3 += hi;
            unpk(u2.z, lo, hi); a4 += lo; a5 += hi;
            unpk(u2.w, lo, hi); a6 += lo; a7 += hi;
            unpk(u3.x, lo, hi); a0 += lo; a1 += hi;
            unpk(u3.y, lo, hi); a2 += lo; a3 += hi;
            unpk(u3.z, lo, hi); a4 += lo; a5 += hi;
            unpk(u3.w, lo, hi); a6 += lo; a7 += hi;
            unpk(u4.x, lo, hi); a0 += lo; a1 += hi;
            unpk(u4.y, lo, hi); a2 += lo; a3 += hi;
            unpk(u4.z, lo, hi); a4 += lo; a5 += hi;
            unpk(u4.w, lo, hi); a6 += lo; a7 += hi;
            unpk(u5.x, lo, hi); a0 += lo; a1 += hi;
            unpk(u5.y, lo, hi); a2 += lo; a3 += hi;
            unpk(u5.z, lo, hi); a4 += lo; a5 += hi;
            unpk(u5.w, lo, hi); a6 += lo; a7 += hi;
            unpk(u6.x, lo, hi); a0 += lo; a1 += hi;
            unpk(u6.y, lo, hi); a2 += lo; a3 += hi;
            unpk(u6.z, lo, hi); a4 += lo; a5 += hi;
            unpk(u6.w, lo, hi); a6 += lo; a7 += hi;
            unpk(u7.x, lo, hi); a0 += lo; a1 += hi;
            unpk(u7.y, lo, hi); a2 += lo; a3 += hi;
            unpk(u7.z, lo, hi); a4 += lo; a5 += hi;
            unpk(u7.w, lo, hi); a6 += lo; a7 += hi;
        }
        if (j + 4 <= end) {
            int s0 = elist[j], s1 = elist[j + 1], s2 = elist[j + 2], s3 = elist[j + 3];
            uint4 u0 = *((const uint4*)(hin + (size_t)s0 * CDIM + li * 8));
            uint4 u1 = *((const uint4*)(hin + (size_t)s1 * CDIM + li * 8));
            uint4 u2 = *((const uint4*)(hin + (size_t)s2 * CDIM + li * 8));
            uint4 u3 = *((const uint4*)(hin + (size_t)s3 * CDIM + li * 8));
            float lo, hi;
            unpk(u0.x, lo, hi); a0 += lo; a1 += hi;
            unpk(u0.y, lo, hi); a2 += lo; a3 += hi;
            unpk(u0.z, lo, hi); a4 += lo; a5 += hi;
            unpk(u0.w, lo, hi); a6 += lo; a7 += hi;
            unpk(u1.x, lo, hi); a0 += lo; a1 += hi;
            unpk(u1.y, lo, hi); a2 += lo; a3 += hi;
            unpk(u1.z, lo, hi); a4 += lo; a5 += hi;
            unpk(u1.w, lo, hi); a6 += lo; a7 += hi;
            unpk(u2.x, lo, hi); a0 += lo; a1 += hi;
            unpk(u2.y, lo, hi); a2 += lo; a3 += hi;
            unpk(u2.z, lo, hi); a4 += lo; a5 += hi;
            unpk(u2.w, lo, hi); a6 += lo; a7 += hi;
            unpk(u3.x, lo, hi); a0 += lo; a1 += hi;
            unpk(u3.y, lo, hi); a2 += lo; a3 += hi;
            unpk(u3.z, lo, hi); a4 += lo; a5 += hi;
            unpk(u3.w, lo, hi); a6 += lo; a7 += hi;
            j += 4;
        }
        for (; j < end; ++j) {
            int s0 = elist[j];
            uint4 u0 = *((const uint4*)(hin + (size_t)s0 * CDIM + li * 8));
            float lo, hi;
            unpk(u0.x, lo, hi); a0 += lo; a1 += hi;
            unpk(u0.y, lo, hi); a2 += lo; a3 += hi;
            unpk(u0.z, lo, hi); a4 += lo; a5 += hi;
            unpk(u0.w, lo, hi); a6 += lo; a7 += hi;
        }
        a0 += __shfl_xor(a0, 16); a1 += __shfl_xor(a1, 16);
        a2 += __shfl_xor(a2, 16); a3 += __shfl_xor(a3, 16);
        a4 += __shfl_xor(a4, 16); a5 += __shfl_xor(a5, 16);
        a6 += __shfl_xor(a6, 16); a7 += __shfl_xor(a7, 16);
        if (sub == 0) {
            float rin = 1.0f / fmaxf((float)(end - beg), 1.0f);
            uint4 o;
            o.x = pk2(a0 * rin, a1 * rin);
            o.y = pk2(a2 * rin, a3 * rin);
            o.z = pk2(a4 * rin, a5 * rin);
            o.w = pk2(a6 * rin, a7 * rin);
            *((uint4*)&sA[r][li * 8]) = o;
        }
    }

    // stage own rows (bf16 copy)
    for (int it = 0; it < 4; ++it) {
        int idx = it * 256 + tid;
        int r = idx >> 5;
        int c4 = idx & 31;
        uint2 u = ((const uint2*)(hin + (size_t)(row0 + r) * CDIM))[c4];
        *((uint2*)&sH[r][c4 * 4]) = u;
    }
    __syncthreads();

    int wave = tid >> 6;
    int wl   = tid & 63;
    int ln16 = wl & 15;
    int quad = wl >> 4;

    floatx4 acc[2][2];
#pragma unroll
    for (int mt = 0; mt < 2; ++mt)
#pragma unroll
        for (int nt = 0; nt < 2; ++nt) acc[mt][nt] = (floatx4)0.0f;

    const unsigned short* wbase = wcat + ((size_t)(wave * 32 + ln16) * 256 + quad * 8);

#pragma unroll
    for (int kb = 0; kb < 8; ++kb) {
        int koff = (kb & 3) * 32 + quad * 8;
        const unsigned short* sbuf = (kb < 4) ? &sA[0][0] : &sH[0][0];
        short8 a0 = *((const short8*)(sbuf + (ln16)      * LPAD + koff));
        short8 a1 = *((const short8*)(sbuf + (ln16 + 16) * LPAD + koff));
        short8 b0 = *((const short8*)(wbase + kb * 32));
        short8 b1 = *((const short8*)(wbase + 16 * 256 + kb * 32));
        acc[0][0] = __builtin_amdgcn_mfma_f32_16x16x32_bf16(a0, b0, acc[0][0], 0, 0, 0);
        acc[1][0] = __builtin_amdgcn_mfma_f32_16x16x32_bf16(a1, b0, acc[1][0], 0, 0, 0);
        acc[0][1] = __builtin_amdgcn_mfma_f32_16x16x32_bf16(a0, b1, acc[0][1], 0, 0, 0);
        acc[1][1] = __builtin_amdgcn_mfma_f32_16x16x32_bf16(a1, b1, acc[1][1], 0, 0, 0);
    }

    __syncthreads();
#pragma unroll
    for (int nt = 0; nt < 2; ++nt) {
        int col = wave * 32 + nt * 16 + ln16;
        float bb = bl[col];
        float ss = scale[col];
        float tt = shift[col];
#pragma unroll
        for (int mt = 0; mt < 2; ++mt) {
#pragma unroll
            for (int r = 0; r < 4; ++r) {
                float v = fmaxf(acc[mt][nt][r] + bb, 0.0f) * ss + tt;
                sA[mt * 16 + quad * 4 + r][col] = f2bf(v);
            }
        }
    }
    __syncthreads();
#pragma unroll
    for (int it = 0; it < 2; ++it) {
        int idx = it * 256 + tid;
        int r = idx >> 4;
        int c = idx & 15;
        uint4 u = *((const uint4*)&sA[r][c * 8]);
        *((uint4*)(hout + (size_t)(row0 + r) * CDIM + c * 8)) = u;
    }
}

// ---------------------------------------------------------------------------
// Fused MLP head (unchanged)
// ---------------------------------------------------------------------------
__global__ __launch_bounds__(256, 4) void head_fused(const unsigned short* __restrict__ hin,
                                                     const unsigned short* __restrict__ wh1,
                                                     const unsigned short* __restrict__ wh2,
                                                     const float* __restrict__ cb1,
                                                     const float* __restrict__ s1,
                                                     const float* __restrict__ t1,
                                                     const float* __restrict__ cb2,
                                                     const float* __restrict__ s2,
                                                     const float* __restrict__ t2,
                                                     const float* __restrict__ W3,
                                                     const float* __restrict__ b3,
                                                     float* __restrict__ out) {
    __shared__ unsigned short sZ[64][LPAD];
    __shared__ float sP[4][64];
    __shared__ float sw3[64];

    int row0 = blockIdx.x * 64;
    int tid = threadIdx.x;
    if (tid < 64) sw3[tid] = W3[tid];

    for (int it = 0; it < 4; ++it) {
        int idx = it * 256 + tid;
        int r = idx >> 4;
        int c = idx & 15;
        uint4 u = *((const uint4*)(hin + (size_t)(row0 + r) * CDIM + c * 8));
        *((uint4*)&sZ[r][c * 8]) = u;
    }
    __syncthreads();

    int wave = tid >> 6;
    int wl   = tid & 63;
    int ln16 = wl & 15;
    int quad = wl >> 4;

    floatx4 a1[4][2];
#pragma unroll
    for (int mt = 0; mt < 4; ++mt) { a1[mt][0] = (floatx4)0.0f; a1[mt][1] = (floatx4)0.0f; }

    const unsigned short* w1a = wh1 + (size_t)(wave * 32 + ln16) * 128 + quad * 8;
    const unsigned short* w1b = w1a + 16 * 128;

#pragma unroll
    for (int kb = 0; kb < 4; ++kb) {
        int koff = kb * 32 + quad * 8;
        short8 b0 = *((const short8*)(w1a + kb * 32));
        short8 b1 = *((const short8*)(w1b + kb * 32));
#pragma unroll
        for (int mt = 0; mt < 4; ++mt) {
            short8 af = *((const short8*)(&sZ[mt * 16 + ln16][koff]));
            a1[mt][0] = __builtin_amdgcn_mfma_f32_16x16x32_bf16(af, b0, a1[mt][0], 0, 0, 0);
            a1[mt][1] = __builtin_amdgcn_mfma_f32_16x16x32_bf16(af, b1, a1[mt][1], 0, 0, 0);
        }
    }

    __syncthreads();
#pragma unroll
    for (int nt = 0; nt < 2; ++nt) {
        int col = wave * 32 + nt * 16 + ln16;
        float bb = cb1[col], ss = s1[col], tt = t1[col];
#pragma unroll
        for (int mt = 0; mt < 4; ++mt) {
#pragma unroll
            for (int r = 0; r < 4; ++r) {
                float v = fmaxf((a1[mt][nt][r] + bb) * ss + tt, 0.0f);
                sZ[mt * 16 + quad * 4 + r][col] = f2bf(v);
            }
        }
    }
    __syncthreads();

    floatx4 a2[4];
#pragma unroll
    for (int mt = 0; mt < 4; ++mt) a2[mt] = (floatx4)0.0f;

    const unsigned short* w2a = wh2 + (size_t)(wave * 16 + ln16) * 128 + quad * 8;

#pragma unroll
    for (int kb = 0; kb < 4; ++kb) {
        int koff = kb * 32 + quad * 8;
        short8 b0 = *((const short8*)(w2a + kb * 32));
#pragma unroll
        for (int mt = 0; mt < 4; ++mt) {
            short8 af = *((const short8*)(&sZ[mt * 16 + ln16][koff]));
            a2[mt] = __builtin_amdgcn_mfma_f32_16x16x32_bf16(af, b0, a2[mt], 0, 0, 0);
        }
    }

    {
        int col = wave * 16 + ln16;
        float bb = cb2[col], ss = s2[col], tt = t2[col];
        float w3v = sw3[col];
#pragma unroll
        for (int mt = 0; mt < 4; ++mt) {
#pragma unroll
            for (int r = 0; r < 4; ++r) {
                float v = fmaxf((a2[mt][r] + bb) * ss + tt, 0.0f) * w3v;
                v += __shfl_xor(v, 1);
                v += __shfl_xor(v, 2);
                v += __shfl_xor(v, 4);
                v += __shfl_xor(v, 8);
                if (ln16 == 0) sP[wave][mt * 16 + quad * 4 + r] = v;
            }
        }
    }
    __syncthreads();
    if (tid < 64) {
        int row = row0 + tid;
        if (row < BATCH)
            out[row] = sP[0][tid] + sP[1][tid] + sP[2][tid] + sP[3][tid] + b3[0];
    }
}

// ---------------------------------------------------------------------------
extern "C" void kernel_launch(void* const* d_in, const int* in_sizes, int n_in,
                              void* d_out, int out_size, void* d_ws, size_t ws_size,
                              hipStream_t stream) {
    const float* x    = (const float*)d_in[0];
    const int*   ei   = (const int*)d_in[1];
    const float* Wl   = (const float*)d_in[3];
    const float* bl   = (const float*)d_in[4];
    const float* Wr   = (const float*)d_in[5];
    const float* bn_g = (const float*)d_in[6];
    const float* bn_b = (const float*)d_in[7];
    const float* bn_m = (const float*)d_in[8];
    const float* bn_v = (const float*)d_in[9];
    const float* cW1  = (const float*)d_in[10];
    const float* cb1  = (const float*)d_in[11];
    const float* cg1  = (const float*)d_in[12];
    const float* cbe1 = (const float*)d_in[13];
    const float* cm1  = (const float*)d_in[14];
    const float* cv1  = (const float*)d_in[15];
    const float* cW2  = (const float*)d_in[16];
    const float* cb2  = (const float*)d_in[17];
    const float* cg2  = (const float*)d_in[18];
    const float* cbe2 = (const float*)d_in[19];
    const float* cm2  = (const float*)d_in[20];
    const float* cv2  = (const float*)d_in[21];
    const float* cW3  = (const float*)d_in[22];
    const float* cb3  = (const float*)d_in[23];

    float* ws  = (float*)d_ws;
    unsigned short* xb  = (unsigned short*)ws;
    unsigned short* hb0 = (unsigned short*)(ws + OFF_HB0);
    unsigned short* hb1 = (unsigned short*)(ws + OFF_HB1);
    float* sc    = ws + OFF_SC;
    int* rowptr  = (int*)(ws + OFF_RP);
    int* bcnt    = (int*)(ws + OFF_BCNT);
    int* elist   = (int*)(ws + OFF_ELIST);
    unsigned int* ebuf = (unsigned int*)(ws + OFF_EBUF);
    unsigned short* wcat = (unsigned short*)(ws + OFF_WCAT);
    unsigned short* wh1  = (unsigned short*)(ws + OFF_WH1);
    unsigned short* wh2  = (unsigned short*)(ws + OFF_WH2);

    setup_all<<<XBLK + WBLK + HBLK + 1, 256, 0, stream>>>(
        x, Wl, Wr, cW1, cW2,
        bn_g, bn_b, bn_m, bn_v,
        cg1, cbe1, cm1, cv1,
        cg2, cbe2, cm2, cv2, ws);

    bucket_fill<<<NEB, 256, 0, stream>>>(ei, bcnt, ebuf);
    bucket_csr<<<NBUCK, 256, 0, stream>>>(ebuf, bcnt, elist, rowptr);

    const unsigned short* lin[NLAYERS] = { xb, hb0, hb1 };
    unsigned short* lout[NLAYERS]      = { hb0, hb1, hb0 };
    for (int l = 0; l < NLAYERS; ++l) {
        sage_fused<<<N_NODES / 32, 256, 0, stream>>>(
            rowptr, elist, lin[l], lout[l],
            wcat + (size_t)l * CDIM * 256,
            bl + (size_t)l * CDIM,
            sc + l * CDIM, sc + 384 + l * CDIM);
    }

    head_fused<<<(BATCH + 63) / 64, 256, 0, stream>>>(
        hb0, wh1, wh2,
        cb1, sc + 768, sc + 896,
        cb2, sc + 1024, sc + 1088,
        cW3, cb3, (float*)d_out);
}

// Round 15
// 411.785 us; speedup vs baseline: 1.4805x; 1.4805x over previous
//
#include <hip/hip_runtime.h>

#define N_NODES 100000
#define N_EDGES 1600000
#define CDIM    128
#define BATCH   50000
#define NLAYERS 3
#define EPS_BN  1e-5f
#define LPAD    136   // LDS row stride in bf16 elems (272 B)

#define NBUCK   512
#define BW      196     // 512*196 = 100352 >= N_NODES
#define EPB     4096    // edges per block in bucket_fill
#define NEB     ((N_EDGES + EPB - 1) / EPB)   // 391
#define EBCAP   3584    // fixed ebuf slots/bucket (mean 3125, sd 56 -> +8 sigma)

typedef __attribute__((ext_vector_type(8))) short short8;   // 8 bf16
typedef __attribute__((ext_vector_type(4))) float floatx4;  // MFMA acc

__device__ __forceinline__ unsigned short f2bf(float f) {
    unsigned int u = __float_as_uint(f);
    u = u + 0x7FFFu + ((u >> 16) & 1u);   // RTNE
    return (unsigned short)(u >> 16);
}
__device__ __forceinline__ void unpk(unsigned int u, float& lo, float& hi) {
    lo = __uint_as_float(u << 16);
    hi = __uint_as_float(u & 0xFFFF0000u);
}
__device__ __forceinline__ unsigned int pk2(float lo, float hi) {
    return (unsigned int)f2bf(lo) | ((unsigned int)f2bf(hi) << 16);
}

// Workspace float-offsets.
// CRITICAL (R11 lesson): hb0/hb1 bases MUST be 256-B aligned (2 lines/row).
// CRITICAL (R14 lesson): gather depth 4 only — depth 8 spills under the
// (256,8) 64-VGPR cap (WRITE_SIZE 25->213 MB scratch signature).
#define OFF_HB0   6400000
#define OFF_HB1   12800000
#define OFF_SC    19200000
#define OFF_RP    19201152   // rowptr, N+1 ints
#define OFF_BCNT  19301184   // 512 (count, fixed-region cursor)
#define OFF_ELIST 19302752   // E ints (exact, contiguous)
#define OFF_EBUF  20902752   // 512*3584 packed uints
#define OFF_WCAT  22737760   // 3*128*256 bf16
#define OFF_WH1   22786912   // 128*128 bf16
#define OFF_WH2   22795104   // 64*128 bf16

// ---------------------------------------------------------------------------
// Mega setup kernel: convert_x / convert_w / convert_whead / fold_bn + bcnt=0
// ---------------------------------------------------------------------------
#define XBLK 12500
#define WBLK 384
#define HBLK 96
__global__ __launch_bounds__(256) void setup_all(
        const float* __restrict__ x,
        const float* __restrict__ Wl, const float* __restrict__ Wr,
        const float* __restrict__ cW1, const float* __restrict__ cW2,
        const float* __restrict__ g, const float* __restrict__ b,
        const float* __restrict__ m, const float* __restrict__ v,
        const float* __restrict__ cg1, const float* __restrict__ cbe1,
        const float* __restrict__ cm1, const float* __restrict__ cv1,
        const float* __restrict__ cg2, const float* __restrict__ cbe2,
        const float* __restrict__ cm2, const float* __restrict__ cv2,
        float* __restrict__ ws) {
    int blk = blockIdx.x;
    int tid = threadIdx.x;
    unsigned short* xb = (unsigned short*)ws;

    if (blk < XBLK) {
        int i = blk * 256 + tid;
        float4 vv = ((const float4*)x)[i];
        ushort4 o;
        o.x = f2bf(vv.x); o.y = f2bf(vv.y); o.z = f2bf(vv.z); o.w = f2bf(vv.w);
        ((ushort4*)xb)[i] = o;
        return;
    }
    if (blk < XBLK + WBLK) {
        unsigned short* wcat = (unsigned short*)(ws + OFF_WCAT);
        int i = (blk - XBLK) * 256 + tid;
        int l = i >> 15;
        int n = (i >> 8) & 127;
        int k = i & 255;
        float w = (k < CDIM) ? Wl[((size_t)l * CDIM + k) * CDIM + n]
                             : Wr[((size_t)l * CDIM + (k - CDIM)) * CDIM + n];
        wcat[i] = f2bf(w);
        return;
    }
    if (blk < XBLK + WBLK + HBLK) {
        unsigned short* wh1 = (unsigned short*)(ws + OFF_WH1);
        unsigned short* wh2 = (unsigned short*)(ws + OFF_WH2);
        int i = (blk - XBLK - WBLK) * 256 + tid;
        if (i < 128 * 128) {
            int n = i >> 7, k = i & 127;
            wh1[i] = f2bf(cW1[k * 128 + n]);
        } else if (i < 128 * 128 + 64 * 128) {
            int j = i - 128 * 128;
            int n = j >> 7, k = j & 127;
            wh2[j] = f2bf(cW2[k * 64 + n]);
        }
        return;
    }
    // misc block: fold BN, zero bcnt
    float* sc = ws + OFF_SC;
    int* bcnt = (int*)(ws + OFF_BCNT);
    for (int i = tid; i < NLAYERS * CDIM; i += 256) {
        float s = g[i] * rsqrtf(v[i] + EPS_BN);
        sc[i] = s;
        sc[NLAYERS * CDIM + i] = b[i] - m[i] * s;
    }
    if (tid < CDIM) {
        float s = cg1[tid] * rsqrtf(cv1[tid] + EPS_BN);
        sc[768 + tid] = s;
        sc[896 + tid] = cbe1[tid] - cm1[tid] * s;
    }
    if (tid < 64) {
        float s = cg2[tid] * rsqrtf(cv2[tid] + EPS_BN);
        sc[1024 + tid] = s;
        sc[1088 + tid] = cbe2[tid] - cm2[tid] * s;
    }
    for (int i = tid; i < NBUCK; i += 256) bcnt[i] = 0;
}

// ---------------------------------------------------------------------------
// bucket_fill: fixed per-bucket ebuf regions (b*EBCAP); bcnt = cursor+count.
// int4 ei reads + LDS-cached bucket ids.
// ---------------------------------------------------------------------------
__global__ __launch_bounds__(256) void bucket_fill(const int* __restrict__ ei,
                                                   int* __restrict__ bcnt,
                                                   unsigned int* __restrict__ ebuf) {
    __shared__ unsigned int st[EPB];      // 16 KB
    __shared__ unsigned short sb[EPB];    // 8 KB
    __shared__ int lh[NBUCK];
    __shared__ int gb[NBUCK];
    __shared__ int lc[NBUCK];
    int tid = threadIdx.x;
    for (int t = tid; t < NBUCK; t += 256) { lh[t] = 0; lc[t] = 0; }
    __syncthreads();
    int base = blockIdx.x * EPB;
    int cnt = min(EPB, N_EDGES - base);    // always multiple of 4
    for (int k = tid; k < cnt / 4; k += 256) {
        int4 s4 = ((const int4*)(ei + base))[k];
        int4 d4 = ((const int4*)(ei + N_EDGES + base))[k];
        int i0 = k * 4;
#pragma unroll
        for (int q = 0; q < 4; ++q) {
            int s = (q == 0) ? s4.x : (q == 1) ? s4.y : (q == 2) ? s4.z : s4.w;
            int d = (q == 0) ? d4.x : (q == 1) ? d4.y : (q == 2) ? d4.z : d4.w;
            int bk = (unsigned)d / BW;
            int ld = d - bk * BW;
            st[i0 + q] = (unsigned)s | ((unsigned)ld << 17);
            sb[i0 + q] = (unsigned short)bk;
            atomicAdd(&lh[bk], 1);
        }
    }
    __syncthreads();
    for (int t = tid; t < NBUCK; t += 256) {
        int c = lh[t];
        gb[t] = c ? (t * EBCAP + atomicAdd(&bcnt[t], c)) : 0;
    }
    __syncthreads();
    for (int i = tid; i < cnt; i += 256) {
        int bk = sb[i];
        int pos = gb[bk] + atomicAdd(&lc[bk], 1);
        ebuf[pos] = st[i];
    }
}

// ---------------------------------------------------------------------------
// bucket_csr: one block per bucket. Internal 512-wide scan of bcnt gives the
// exact elist base (no separate scan dispatch). Local per-dst CSR in LDS,
// coalesced elist/rowptr out.
// ---------------------------------------------------------------------------
__global__ __launch_bounds__(256) void bucket_csr(const unsigned int* __restrict__ ebuf,
                                                  const int* __restrict__ bcnt,
                                                  int* __restrict__ elist,
                                                  int* __restrict__ rowptr) {
    __shared__ int sbb[NBUCK];            // 2 KB: bucket-count prefix
    __shared__ unsigned int st[EBCAP];    // 14 KB
    __shared__ int out[EBCAP];            // 14 KB
    __shared__ int h[256], sscan[256], pre[256], cur[256];
    int b = blockIdx.x;
    int tid = threadIdx.x;
    int cnt = min(bcnt[b], EBCAP);

    // inclusive scan of all 512 bucket counts (256 threads x 2 elems)
    sbb[tid] = bcnt[tid];
    sbb[tid + 256] = bcnt[tid + 256];
    h[tid] = 0; cur[tid] = 0;
    __syncthreads();
    for (int off = 1; off < NBUCK; off <<= 1) {
        int v0 = (tid >= off) ? sbb[tid - off] : 0;
        int t2 = tid + 256;
        int v1 = sbb[t2 - off];   // t2 >= 256 > off always
        __syncthreads();
        sbb[tid] += v0;
        sbb[t2] += v1;
        __syncthreads();
    }
    int obase = (b == 0) ? 0 : sbb[b - 1];

    int ebase = b * EBCAP;
    for (int i = tid; i < cnt; i += 256) {
        unsigned int u = ebuf[ebase + i];
        st[i] = u;
        atomicAdd(&h[u >> 17], 1);
    }
    __syncthreads();
    sscan[tid] = h[tid];
    __syncthreads();
    for (int off = 1; off < 256; off <<= 1) {
        int v = (tid >= off) ? sscan[tid - off] : 0;
        __syncthreads();
        sscan[tid] += v;
        __syncthreads();
    }
    pre[tid] = sscan[tid] - h[tid];
    __syncthreads();
    for (int i = tid; i < cnt; i += 256) {
        unsigned int u = st[i];
        int ld = u >> 17;
        int pos = pre[ld] + atomicAdd(&cur[ld], 1);
        out[pos] = (int)(u & 0x1FFFFu);
    }
    __syncthreads();
    for (int i = tid; i < cnt; i += 256) elist[obase + i] = out[i];
    int gn = b * BW + tid;
    if (tid < BW && gn < N_NODES) rowptr[gn] = obase + pre[tid];
    if (b == 0 && tid == 0) rowptr[N_NODES] = N_EDGES;
}

// ---------------------------------------------------------------------------
// Fused SAGE layer — proven R12/R13 4-deep gather (82 µs / 187 MB):
// 2 sub-halves x 4-edge chunks, scalar elist loads, scalar tail,
// MFMA GEMM, LDS-staged coalesced bf16 C store.
// ---------------------------------------------------------------------------
__global__ __launch_bounds__(256, 8) void sage_fused(const int* __restrict__ rowptr,
                                                     const int* __restrict__ elist,
                                                     const unsigned short* __restrict__ hin,
                                                     unsigned short* __restrict__ hout,
                                                     const unsigned short* __restrict__ wcat,
                                                     const float* __restrict__ bl,
                                                     const float* __restrict__ scale,
                                                     const float* __restrict__ shift) {
    __shared__ unsigned short sA[32][LPAD];
    __shared__ unsigned short sH[32][LPAD];

    int row0 = blockIdx.x * 32;
    int tid = threadIdx.x;
    int lane = tid & 31;
    int grp = tid >> 5;       // 8 node-groups
    int sub = lane >> 4;      // 0/1: chunk parity
    int li  = lane & 15;      // 16 lanes x 8 channels

    for (int rr = 0; rr < 4; ++rr) {
        int r = rr * 8 + grp;
        int node = row0 + r;
        int beg = rowptr[node];
        int end = rowptr[node + 1];
        float a0 = 0.f, a1 = 0.f, a2 = 0.f, a3 = 0.f,
              a4 = 0.f, a5 = 0.f, a6 = 0.f, a7 = 0.f;
        int j = beg + sub * 4;
        for (; j + 4 <= end; j += 8) {
            int s0 = elist[j], s1 = elist[j + 1], s2 = elist[j + 2], s3 = elist[j + 3];
            uint4 u0 = *((const uint4*)(hin + (size_t)s0 * CDIM + li * 8));
            uint4 u1 = *((const uint4*)(hin + (size_t)s1 * CDIM + li * 8));
            uint4 u2 = *((const uint4*)(hin + (size_t)s2 * CDIM + li * 8));
            uint4 u3 = *((const uint4*)(hin + (size_t)s3 * CDIM + li * 8));
            float lo, hi;
            unpk(u0.x, lo, hi); a0 += lo; a1 += hi;
            unpk(u0.y, lo, hi); a2 += lo; a3 += hi;
            unpk(u0.z, lo, hi); a4 += lo; a5 += hi;
            unpk(u0.w, lo, hi); a6 += lo; a7 += hi;
            unpk(u1.x, lo, hi); a0 += lo; a1 += hi;
            unpk(u1.y, lo, hi); a2 += lo; a3 += hi;
            unpk(u1.z, lo, hi); a4 += lo; a5 += hi;
            unpk(u1.w, lo, hi); a6 += lo; a7 += hi;
            unpk(u2.x, lo, hi); a0 += lo; a1 += hi;
            unpk(u2.y, lo, hi); a2 += lo; a3 += hi;
            unpk(u2.z, lo, hi); a4 += lo; a5 += hi;
            unpk(u2.w, lo, hi); a6 += lo; a7 += hi;
            unpk(u3.x, lo, hi); a0 += lo; a1 += hi;
            unpk(u3.y, lo, hi); a2 += lo; a3 += hi;
            unpk(u3.z, lo, hi); a4 += lo; a5 += hi;
            unpk(u3.w, lo, hi); a6 += lo; a7 += hi;
        }
        for (; j < end; ++j) {
            int s0 = elist[j];
            uint4 u0 = *((const uint4*)(hin + (size_t)s0 * CDIM + li * 8));
            float lo, hi;
            unpk(u0.x, lo, hi); a0 += lo; a1 += hi;
            unpk(u0.y, lo, hi); a2 += lo; a3 += hi;
            unpk(u0.z, lo, hi); a4 += lo; a5 += hi;
            unpk(u0.w, lo, hi); a6 += lo; a7 += hi;
        }
        a0 += __shfl_xor(a0, 16); a1 += __shfl_xor(a1, 16);
        a2 += __shfl_xor(a2, 16); a3 += __shfl_xor(a3, 16);
        a4 += __shfl_xor(a4, 16); a5 += __shfl_xor(a5, 16);
        a6 += __shfl_xor(a6, 16); a7 += __shfl_xor(a7, 16);
        if (sub == 0) {
            float rin = 1.0f / fmaxf((float)(end - beg), 1.0f);
            uint4 o;
            o.x = pk2(a0 * rin, a1 * rin);
            o.y = pk2(a2 * rin, a3 * rin);
            o.z = pk2(a4 * rin, a5 * rin);
            o.w = pk2(a6 * rin, a7 * rin);
            *((uint4*)&sA[r][li * 8]) = o;
        }
    }

    // stage own rows (bf16 copy)
    for (int it = 0; it < 4; ++it) {
        int idx = it * 256 + tid;
        int r = idx >> 5;
        int c4 = idx & 31;
        uint2 u = ((const uint2*)(hin + (size_t)(row0 + r) * CDIM))[c4];
        *((uint2*)&sH[r][c4 * 4]) = u;
    }
    __syncthreads();

    int wave = tid >> 6;
    int wl   = tid & 63;
    int ln16 = wl & 15;
    int quad = wl >> 4;

    floatx4 acc[2][2];
#pragma unroll
    for (int mt = 0; mt < 2; ++mt)
#pragma unroll
        for (int nt = 0; nt < 2; ++nt) acc[mt][nt] = (floatx4)0.0f;

    const unsigned short* wbase = wcat + ((size_t)(wave * 32 + ln16) * 256 + quad * 8);

#pragma unroll
    for (int kb = 0; kb < 8; ++kb) {
        int koff = (kb & 3) * 32 + quad * 8;
        const unsigned short* sbuf = (kb < 4) ? &sA[0][0] : &sH[0][0];
        short8 a0 = *((const short8*)(sbuf + (ln16)      * LPAD + koff));
        short8 a1 = *((const short8*)(sbuf + (ln16 + 16) * LPAD + koff));
        short8 b0 = *((const short8*)(wbase + kb * 32));
        short8 b1 = *((const short8*)(wbase + 16 * 256 + kb * 32));
        acc[0][0] = __builtin_amdgcn_mfma_f32_16x16x32_bf16(a0, b0, acc[0][0], 0, 0, 0);
        acc[1][0] = __builtin_amdgcn_mfma_f32_16x16x32_bf16(a1, b0, acc[1][0], 0, 0, 0);
        acc[0][1] = __builtin_amdgcn_mfma_f32_16x16x32_bf16(a0, b1, acc[0][1], 0, 0, 0);
        acc[1][1] = __builtin_amdgcn_mfma_f32_16x16x32_bf16(a1, b1, acc[1][1], 0, 0, 0);
    }

    __syncthreads();
#pragma unroll
    for (int nt = 0; nt < 2; ++nt) {
        int col = wave * 32 + nt * 16 + ln16;
        float bb = bl[col];
        float ss = scale[col];
        float tt = shift[col];
#pragma unroll
        for (int mt = 0; mt < 2; ++mt) {
#pragma unroll
            for (int r = 0; r < 4; ++r) {
                float v = fmaxf(acc[mt][nt][r] + bb, 0.0f) * ss + tt;
                sA[mt * 16 + quad * 4 + r][col] = f2bf(v);
            }
        }
    }
    __syncthreads();
#pragma unroll
    for (int it = 0; it < 2; ++it) {
        int idx = it * 256 + tid;
        int r = idx >> 4;
        int c = idx & 15;
        uint4 u = *((const uint4*)&sA[r][c * 8]);
        *((uint4*)(hout + (size_t)(row0 + r) * CDIM + c * 8)) = u;
    }
}

// ---------------------------------------------------------------------------
// Fused MLP head (unchanged)
// ---------------------------------------------------------------------------
__global__ __launch_bounds__(256, 4) void head_fused(const unsigned short* __restrict__ hin,
                                                     const unsigned short* __restrict__ wh1,
                                                     const unsigned short* __restrict__ wh2,
                                                     const float* __restrict__ cb1,
                                                     const float* __restrict__ s1,
                                                     const float* __restrict__ t1,
                                                     const float* __restrict__ cb2,
                                                     const float* __restrict__ s2,
                                                     const float* __restrict__ t2,
                                                     const float* __restrict__ W3,
                                                     const float* __restrict__ b3,
                                                     float* __restrict__ out) {
    __shared__ unsigned short sZ[64][LPAD];
    __shared__ float sP[4][64];
    __shared__ float sw3[64];

    int row0 = blockIdx.x * 64;
    int tid = threadIdx.x;
    if (tid < 64) sw3[tid] = W3[tid];

    for (int it = 0; it < 4; ++it) {
        int idx = it * 256 + tid;
        int r = idx >> 4;
        int c = idx & 15;
        uint4 u = *((const uint4*)(hin + (size_t)(row0 + r) * CDIM + c * 8));
        *((uint4*)&sZ[r][c * 8]) = u;
    }
    __syncthreads();

    int wave = tid >> 6;
    int wl   = tid & 63;
    int ln16 = wl & 15;
    int quad = wl >> 4;

    floatx4 a1[4][2];
#pragma unroll
    for (int mt = 0; mt < 4; ++mt) { a1[mt][0] = (floatx4)0.0f; a1[mt][1] = (floatx4)0.0f; }

    const unsigned short* w1a = wh1 + (size_t)(wave * 32 + ln16) * 128 + quad * 8;
    const unsigned short* w1b = w1a + 16 * 128;

#pragma unroll
    for (int kb = 0; kb < 4; ++kb) {
        int koff = kb * 32 + quad * 8;
        short8 b0 = *((const short8*)(w1a + kb * 32));
        short8 b1 = *((const short8*)(w1b + kb * 32));
#pragma unroll
        for (int mt = 0; mt < 4; ++mt) {
            short8 af = *((const short8*)(&sZ[mt * 16 + ln16][koff]));
            a1[mt][0] = __builtin_amdgcn_mfma_f32_16x16x32_bf16(af, b0, a1[mt][0], 0, 0, 0);
            a1[mt][1] = __builtin_amdgcn_mfma_f32_16x16x32_bf16(af, b1, a1[mt][1], 0, 0, 0);
        }
    }

    __syncthreads();
#pragma unroll
    for (int nt = 0; nt < 2; ++nt) {
        int col = wave * 32 + nt * 16 + ln16;
        float bb = cb1[col], ss = s1[col], tt = t1[col];
#pragma unroll
        for (int mt = 0; mt < 4; ++mt) {
#pragma unroll
            for (int r = 0; r < 4; ++r) {
                float v = fmaxf((a1[mt][nt][r] + bb) * ss + tt, 0.0f);
                sZ[mt * 16 + quad * 4 + r][col] = f2bf(v);
            }
        }
    }
    __syncthreads();

    floatx4 a2[4];
#pragma unroll
    for (int mt = 0; mt < 4; ++mt) a2[mt] = (floatx4)0.0f;

    const unsigned short* w2a = wh2 + (size_t)(wave * 16 + ln16) * 128 + quad * 8;

#pragma unroll
    for (int kb = 0; kb < 4; ++kb) {
        int koff = kb * 32 + quad * 8;
        short8 b0 = *((const short8*)(w2a + kb * 32));
#pragma unroll
        for (int mt = 0; mt < 4; ++mt) {
            short8 af = *((const short8*)(&sZ[mt * 16 + ln16][koff]));
            a2[mt] = __builtin_amdgcn_mfma_f32_16x16x32_bf16(af, b0, a2[mt], 0, 0, 0);
        }
    }

    {
        int col = wave * 16 + ln16;
        float bb = cb2[col], ss = s2[col], tt = t2[col];
        float w3v = sw3[col];
#pragma unroll
        for (int mt = 0; mt < 4; ++mt) {
#pragma unroll
            for (int r = 0; r < 4; ++r) {
                float v = fmaxf((a2[mt][r] + bb) * ss + tt, 0.0f) * w3v;
                v += __shfl_xor(v, 1);
                v += __shfl_xor(v, 2);
                v += __shfl_xor(v, 4);
                v += __shfl_xor(v, 8);
                if (ln16 == 0) sP[wave][mt * 16 + quad * 4 + r] = v;
            }
        }
    }
    __syncthreads();
    if (tid < 64) {
        int row = row0 + tid;
        if (row < BATCH)
            out[row] = sP[0][tid] + sP[1][tid] + sP[2][tid] + sP[3][tid] + b3[0];
    }
}

// ---------------------------------------------------------------------------
extern "C" void kernel_launch(void* const* d_in, const int* in_sizes, int n_in,
                              void* d_out, int out_size, void* d_ws, size_t ws_size,
                              hipStream_t stream) {
    const float* x    = (const float*)d_in[0];
    const int*   ei   = (const int*)d_in[1];
    const float* Wl   = (const float*)d_in[3];
    const float* bl   = (const float*)d_in[4];
    const float* Wr   = (const float*)d_in[5];
    const float* bn_g = (const float*)d_in[6];
    const float* bn_b = (const float*)d_in[7];
    const float* bn_m = (const float*)d_in[8];
    const float* bn_v = (const float*)d_in[9];
    const float* cW1  = (const float*)d_in[10];
    const float* cb1  = (const float*)d_in[11];
    const float* cg1  = (const float*)d_in[12];
    const float* cbe1 = (const float*)d_in[13];
    const float* cm1  = (const float*)d_in[14];
    const float* cv1  = (const float*)d_in[15];
    const float* cW2  = (const float*)d_in[16];
    const float* cb2  = (const float*)d_in[17];
    const float* cg2  = (const float*)d_in[18];
    const float* cbe2 = (const float*)d_in[19];
    const float* cm2  = (const float*)d_in[20];
    const float* cv2  = (const float*)d_in[21];
    const float* cW3  = (const float*)d_in[22];
    const float* cb3  = (const float*)d_in[23];

    float* ws  = (float*)d_ws;
    unsigned short* xb  = (unsigned short*)ws;
    unsigned short* hb0 = (unsigned short*)(ws + OFF_HB0);
    unsigned short* hb1 = (unsigned short*)(ws + OFF_HB1);
    float* sc    = ws + OFF_SC;
    int* rowptr  = (int*)(ws + OFF_RP);
    int* bcnt    = (int*)(ws + OFF_BCNT);
    int* elist   = (int*)(ws + OFF_ELIST);
    unsigned int* ebuf = (unsigned int*)(ws + OFF_EBUF);
    unsigned short* wcat = (unsigned short*)(ws + OFF_WCAT);
    unsigned short* wh1  = (unsigned short*)(ws + OFF_WH1);
    unsigned short* wh2  = (unsigned short*)(ws + OFF_WH2);

    setup_all<<<XBLK + WBLK + HBLK + 1, 256, 0, stream>>>(
        x, Wl, Wr, cW1, cW2,
        bn_g, bn_b, bn_m, bn_v,
        cg1, cbe1, cm1, cv1,
        cg2, cbe2, cm2, cv2, ws);

    bucket_fill<<<NEB, 256, 0, stream>>>(ei, bcnt, ebuf);
    bucket_csr<<<NBUCK, 256, 0, stream>>>(ebuf, bcnt, elist, rowptr);

    const unsigned short* lin[NLAYERS] = { xb, hb0, hb1 };
    unsigned short* lout[NLAYERS]      = { hb0, hb1, hb0 };
    for (int l = 0; l < NLAYERS; ++l) {
        sage_fused<<<N_NODES / 32, 256, 0, stream>>>(
            rowptr, elist, lin[l], lout[l],
            wcat + (size_t)l * CDIM * 256,
            bl + (size_t)l * CDIM,
            sc + l * CDIM, sc + 384 + l * CDIM);
    }

    head_fused<<<(BATCH + 63) / 64, 256, 0, stream>>>(
        hb0, wh1, wh2,
        cb1, sc + 768, sc + 896,
        cb2, sc + 1024, sc + 1088,
        cW3, cb3, (float*)d_out);
}